// Round 1
// baseline (1790.836 us; speedup 1.0000x reference)
//
#include <hip/hip_runtime.h>

// LinearAttentionLayer on MI355X — round 1: fp32 correctness baseline, restructured.
// Pipeline:
//   K_w    : Wcat[1024][3072] = [Wq@Wf (per head) | Wk@Wf | Wv]
//   K_proj : proj[16384][3072] = relu-bias epilogue( x @ Wcat )   (qf | kf | v)
//   K_kv1/2: kv[b,h,64,64] = sum_l kf*v ; ksum[b,h,64] = sum_l kf (chunked partials)
//   K_attn : attn[m, h*64+d] = (qf . kv) / max(qf . ksum, 1e-6)  -> written over kf region
//   K_out  : out = attn @ Wo + bo
// ws usage ~232 MB.

#define D_MODEL 1024
#define N_HEADS 16
#define HEAD_DIM 64
#define FDIM 64
#define BATCH 4
#define SEQ 4096
#define M_ROWS (BATCH * SEQ)   // 16384
#define N3 3072

// ---------------- Wcat build: Wqf | Wkf | Wv ----------------
__global__ __launch_bounds__(256) void build_wcat(
    const float* __restrict__ Wq, const float* __restrict__ Wk,
    const float* __restrict__ Wv, const float* __restrict__ Wf,
    float* __restrict__ wcat)
{
    __shared__ float wf_s[64][65];
    __shared__ float wq_s[1024];
    __shared__ float wk_s[1024];
    int k = blockIdx.x;     // 0..1023 (row of Wq/Wk/Wv)
    int t = threadIdx.x;
    for (int i = t; i < 64 * 64; i += 256) wf_s[i >> 6][i & 63] = Wf[i];
    for (int i = t; i < 1024; i += 256) {
        wq_s[i] = Wq[k * 1024 + i];
        wk_s[i] = Wk[k * 1024 + i];
    }
    __syncthreads();
    for (int n = t; n < 1024; n += 256) {
        int h = n >> 6, f = n & 63;
        const float* wqh = &wq_s[h * 64];
        const float* wkh = &wk_s[h * 64];
        float aq = 0.f, ak = 0.f;
#pragma unroll 16
        for (int e = 0; e < 64; ++e) {
            aq = fmaf(wqh[e], wf_s[e][f], aq);
            ak = fmaf(wkh[e], wf_s[e][f], ak);
        }
        wcat[(size_t)k * N3 + n] = aq;
        wcat[(size_t)k * N3 + 1024 + n] = ak;
    }
    for (int n = t; n < 1024; n += 256) wcat[(size_t)k * N3 + 2048 + n] = Wv[k * 1024 + n];
}

// ---------------- fp32 tiled GEMM 128x128x16, 256 thr, 8x8/thread ----------------
// EPI 0: proj epilogue (cols<2048: relu(x + bf[col&63]))   EPI 1: + bias[col]
template <int EPI>
__global__ __launch_bounds__(256) void gemm128(
    const float* __restrict__ A, int lda,
    const float* __restrict__ Bm, int ldb,
    float* __restrict__ C, int ldc,
    int K, const float* __restrict__ bias)
{
    __shared__ float As[16][132];  // k-major (As[k][m]), padded
    __shared__ float Bs[16][132];
    const int t = threadIdx.x;
    const int m0 = blockIdx.y * 128;
    const int n0 = blockIdx.x * 128;
    const int tx = t & 15, ty = t >> 4;

    const int la_row = t >> 1;          // 0..127
    const int la_k   = (t & 1) * 8;     // 0 or 8
    const int lb_k   = t >> 4;          // 0..15
    const int lb_n   = (t & 15) * 4;    // 0..60

    const float* Aptr = A + (size_t)(m0 + la_row) * lda + la_k;
    const float* Bptr = Bm + (size_t)lb_k * ldb + n0 + lb_n;

    float acc[8][8];
#pragma unroll
    for (int i = 0; i < 8; ++i)
#pragma unroll
        for (int j = 0; j < 8; ++j) acc[i][j] = 0.f;

    const int nk = K / 16;
    float4 pa0 = *(const float4*)(Aptr);
    float4 pa1 = *(const float4*)(Aptr + 4);
    float4 pb0 = *(const float4*)(Bptr);
    float4 pb1 = *(const float4*)(Bptr + 64);

    for (int kt = 0; kt < nk; ++kt) {
        // store staged tile
#pragma unroll
        for (int j = 0; j < 4; ++j) {
            As[la_k + j][la_row]     = ((const float*)&pa0)[j];
            As[la_k + 4 + j][la_row] = ((const float*)&pa1)[j];
        }
        *(float4*)&Bs[lb_k][lb_n]      = pb0;
        *(float4*)&Bs[lb_k][lb_n + 64] = pb1;
        __syncthreads();
        // prefetch next tile into regs (overlaps with compute below)
        if (kt + 1 < nk) {
            pa0 = *(const float4*)(Aptr + (kt + 1) * 16);
            pa1 = *(const float4*)(Aptr + (kt + 1) * 16 + 4);
            pb0 = *(const float4*)(Bptr + (size_t)(kt + 1) * 16 * ldb);
            pb1 = *(const float4*)(Bptr + (size_t)(kt + 1) * 16 * ldb + 64);
        }
#pragma unroll
        for (int k = 0; k < 16; ++k) {
            float4 a0 = *(const float4*)&As[k][ty * 4];
            float4 a1 = *(const float4*)&As[k][64 + ty * 4];
            float4 b0 = *(const float4*)&Bs[k][tx * 4];
            float4 b1 = *(const float4*)&Bs[k][64 + tx * 4];
            float ar[8] = {a0.x, a0.y, a0.z, a0.w, a1.x, a1.y, a1.z, a1.w};
            float br[8] = {b0.x, b0.y, b0.z, b0.w, b1.x, b1.y, b1.z, b1.w};
#pragma unroll
            for (int i = 0; i < 8; ++i)
#pragma unroll
                for (int j = 0; j < 8; ++j)
                    acc[i][j] = fmaf(ar[i], br[j], acc[i][j]);
        }
        __syncthreads();
    }

    // epilogue + store
#pragma unroll
    for (int i = 0; i < 8; ++i) {
        int m = m0 + ((i < 4) ? (ty * 4 + i) : (64 + ty * 4 + (i - 4)));
#pragma unroll
        for (int jj = 0; jj < 2; ++jj) {
            int n_base = n0 + ((jj == 0) ? (tx * 4) : (64 + tx * 4));
            float4 vout;
            float* vp = (float*)&vout;
#pragma unroll
            for (int j = 0; j < 4; ++j) {
                float val = acc[i][jj * 4 + j];
                int n = n_base + j;
                if (EPI == 0) {
                    if (n < 2048) {
                        val = val + bias[n & 63];
                        val = val > 0.f ? val : 0.f;
                    }
                } else {
                    val += bias[n];
                }
                vp[j] = val;
            }
            *(float4*)&C[(size_t)m * ldc + n_base] = vout;
        }
    }
}

// ---------------- kv partial reduction over L chunks ----------------
// grid (c=16, h=16, b=4); each wg reduces 256 rows into kvp[bh][c][64][64], ksp[bh][c][64]
__global__ __launch_bounds__(256) void kv_partial(
    const float* __restrict__ proj, float* __restrict__ kvp, float* __restrict__ ksp)
{
    __shared__ float kf_s[32][64];
    __shared__ float v_s[32][64];
    const int t = threadIdx.x;
    const int c = blockIdx.x, h = blockIdx.y, b = blockIdx.z;
    const int l0 = c * 256;
    const int fq = t >> 4;  // f block: fq*4
    const int dq = t & 15;  // d block: dq*4
    float acc[4][4] = {};
    float ks[4] = {0.f, 0.f, 0.f, 0.f};
    const size_t rowbase = (size_t)b * SEQ * N3;

    for (int lb = 0; lb < 256; lb += 32) {
        __syncthreads();
        for (int i = t; i < 512; i += 256) {
            int r = i >> 4;
            int c4 = (i & 15) * 4;
            const float* rowp = proj + rowbase + (size_t)(l0 + lb + r) * N3 + h * 64;
            *(float4*)&kf_s[r][c4] = *(const float4*)(rowp + 1024 + c4);
            *(float4*)&v_s[r][c4]  = *(const float4*)(rowp + 2048 + c4);
        }
        __syncthreads();
#pragma unroll 8
        for (int l = 0; l < 32; ++l) {
            float4 kf4 = *(const float4*)&kf_s[l][fq * 4];
            float4 v4  = *(const float4*)&v_s[l][dq * 4];
            const float* kfp = (const float*)&kf4;
            const float* vp  = (const float*)&v4;
#pragma unroll
            for (int i = 0; i < 4; ++i) {
#pragma unroll
                for (int j = 0; j < 4; ++j)
                    acc[i][j] = fmaf(kfp[i], vp[j], acc[i][j]);
                if (dq == 0) ks[i] += kfp[i];
            }
        }
    }
    const size_t base = ((size_t)(b * 16 + h) * 16 + c) * 4096;
#pragma unroll
    for (int i = 0; i < 4; ++i)
        *(float4*)&kvp[base + (size_t)(fq * 4 + i) * 64 + dq * 4] = *(float4*)&acc[i][0];
    if (dq == 0) {
        const size_t kb = ((size_t)(b * 16 + h) * 16 + c) * 64;
#pragma unroll
        for (int i = 0; i < 4; ++i) ksp[kb + fq * 4 + i] = ks[i];
    }
}

__global__ __launch_bounds__(256) void kv_reduce(
    const float* __restrict__ kvp, const float* __restrict__ ksp,
    float* __restrict__ kv, float* __restrict__ ksum)
{
    int gid = blockIdx.x * 256 + threadIdx.x;
    if (gid < 64 * 4096) {
        int bh = gid >> 12;
        int fd = gid & 4095;
        float s = 0.f;
#pragma unroll
        for (int c = 0; c < 16; ++c) s += kvp[((size_t)bh * 16 + c) * 4096 + fd];
        kv[gid] = s;
    } else {
        int g = gid - 64 * 4096;  // 0..4095
        int bh = g >> 6;
        int f = g & 63;
        float s = 0.f;
#pragma unroll
        for (int c = 0; c < 16; ++c) s += ksp[((size_t)bh * 16 + c) * 64 + f];
        ksum[g] = s;
    }
}

// ---------------- attn apply: out = (qf . kv) / max(qf . ksum, 1e-6) ----------------
// grid (ltile=32, h=16, b=4); writes into kf region of proj (cols 1024..2047)
__global__ __launch_bounds__(256) void attn_apply(
    float* __restrict__ proj, const float* __restrict__ kv, const float* __restrict__ ksum)
{
    __shared__ float kv_s[64][68];
    __shared__ float qf_s[64][68];
    __shared__ float ks_s[64];
    const int t = threadIdx.x;
    const int b = blockIdx.z, h = blockIdx.y;
    const int l0 = blockIdx.x * 128;
    for (int i = t; i < 4096; i += 256)
        kv_s[i >> 6][i & 63] = kv[(size_t)(b * 16 + h) * 4096 + i];
    if (t < 64) ks_s[t] = ksum[(b * 16 + h) * 64 + t];
    const int rq = t >> 4;  // rows rq*4..rq*4+3 within 64-row batch
    const int dq = t & 15;  // d = dq*4

    for (int rb = 0; rb < 128; rb += 64) {
        __syncthreads();
        for (int i = t; i < 1024; i += 256) {
            int r = i >> 4, c4 = (i & 15) * 4;
            *(float4*)&qf_s[r][c4] =
                *(const float4*)(proj + (size_t)(b * SEQ + l0 + rb + r) * N3 + h * 64 + c4);
        }
        __syncthreads();
        float acc[4][4] = {};
        float nrm[4] = {};
        for (int f = 0; f < 64; f += 4) {
            float4 q4[4];
#pragma unroll
            for (int r = 0; r < 4; ++r) q4[r] = *(const float4*)&qf_s[rq * 4 + r][f];
            float4 kvf[4];
#pragma unroll
            for (int j = 0; j < 4; ++j) kvf[j] = *(const float4*)&kv_s[f + j][dq * 4];
#pragma unroll
            for (int r = 0; r < 4; ++r) {
                const float* qp = (const float*)&q4[r];
#pragma unroll
                for (int j = 0; j < 4; ++j) {
                    const float* kp = (const float*)&kvf[j];
#pragma unroll
                    for (int d = 0; d < 4; ++d)
                        acc[r][d] = fmaf(qp[j], kp[d], acc[r][d]);
                    nrm[r] = fmaf(qp[j], ks_s[f + j], nrm[r]);
                }
            }
        }
#pragma unroll
        for (int r = 0; r < 4; ++r) {
            float n = nrm[r] > 1e-6f ? nrm[r] : 1e-6f;
            float inv = 1.f / n;
            float4 o;
            float* op = (float*)&o;
#pragma unroll
            for (int d = 0; d < 4; ++d) op[d] = acc[r][d] * inv;
            *(float4*)(proj + (size_t)(b * SEQ + l0 + rb + rq * 4 + r) * N3 + 1024 + h * 64 + dq * 4) = o;
        }
    }
}

extern "C" void kernel_launch(void* const* d_in, const int* in_sizes, int n_in,
                              void* d_out, int out_size, void* d_ws, size_t ws_size,
                              hipStream_t stream)
{
    const float* x  = (const float*)d_in[0];
    const float* Wq = (const float*)d_in[1];
    const float* Wk = (const float*)d_in[2];
    const float* Wv = (const float*)d_in[3];
    const float* Wo = (const float*)d_in[4];
    const float* bo = (const float*)d_in[5];
    const float* Wf = (const float*)d_in[6];
    const float* bf = (const float*)d_in[7];
    float* out = (float*)d_out;
    float* ws  = (float*)d_ws;

    // workspace layout (floats), total ~58M floats = 232 MB
    float* wcat = ws;                       // 1024*3072     = 3,145,728
    float* proj = wcat + 3145728;           // 16384*3072    = 50,331,648
    float* kvp  = proj + 50331648;          // 64*16*4096    = 4,194,304
    float* ksp  = kvp + 4194304;            // 64*16*64      = 65,536
    float* kv   = ksp + 65536;              // 64*4096       = 262,144
    float* ksum = kv + 262144;              // 4,096

    build_wcat<<<dim3(1024), 256, 0, stream>>>(Wq, Wk, Wv, Wf, wcat);
    gemm128<0><<<dim3(24, 128), 256, 0, stream>>>(x, 1024, wcat, N3, proj, N3, 1024, bf);
    kv_partial<<<dim3(16, 16, 4), 256, 0, stream>>>(proj, kvp, ksp);
    kv_reduce<<<dim3(1040), 256, 0, stream>>>(kvp, ksp, kv, ksum);
    attn_apply<<<dim3(32, 16, 4), 256, 0, stream>>>(proj, kv, ksum);
    gemm128<1><<<dim3(8, 128), 256, 0, stream>>>(proj + 1024, N3, Wo, 1024, out, 1024, 1024, bo);
}

// Round 4
// 836.654 us; speedup vs baseline: 2.1405x; 2.1405x over previous
//
#include <hip/hip_runtime.h>

// LinearAttentionLayer on MI355X — round 4 (= round 3 resubmit; round 3 never
// ran: GPU acquisition timeout). bf16 split-precision MFMA GEMMs, batch-paired
// to keep workspace <= 198 MB (round-1's 232 MB is the only empirically-safe
// ws footprint; round-2's 358 MB may have overflowed d_ws).
//
// Pipeline (weights once, then per batch-pair p in {0,1}, 8192 rows each):
//   build_wcat : wcat[1024][3072] fp32 = [Wq@Wf | Wk@Wf | Wv]
//   tsplit     : wcat -> wcsT[3072][3072] bf16 (transposed, [hi|hi|lo] along k')
//                Wo   -> wosT[1024][3072] bf16
//   split_x    : x_p -> xs[8192][3072] bf16 ([hi|lo|hi] along k')
//   gemm_bf16<0>: proj[8192][3072] fp32 = relu/bias epi( xs @ wcsT^T )   (qf|kf|v)
//   kv_partial/kv_reduce : kv[2,16,64,64], ksum[2,16,64]
//   attn_apply : attn = (qf.kv)/max(qf.ksum,1e-6) -> bf16 split into xs region
//   gemm_bf16<1>: out_p = attn @ Wo + bo
// Split-bf16 GEMM: A'=[hi|lo|hi], B'=[hi|hi|lo] => hi*hi + lo*hi + hi*lo (err ~1e-5).

#define D_MODEL 1024
#define N_HEADS 16
#define BATCH 4
#define SEQ 4096
#define N3 3072

typedef short bf16x8 __attribute__((ext_vector_type(8)));
typedef float f32x4 __attribute__((ext_vector_type(4)));
typedef short short4v __attribute__((ext_vector_type(4)));

__device__ __forceinline__ unsigned short f2bf(float v) {
    unsigned u = __float_as_uint(v);
    unsigned r = (u + 0x7FFF + ((u >> 16) & 1)) >> 16;
    return (unsigned short)r;
}
__device__ __forceinline__ float bf2f(unsigned short b) {
    return __uint_as_float((unsigned)b << 16);
}

#define GLOAD16(gp, lp) __builtin_amdgcn_global_load_lds( \
    (const __attribute__((address_space(1))) void*)(gp),  \
    (__attribute__((address_space(3))) void*)(lp), 16, 0, 0)

// ---------------- Wcat build (fp32): Wqf | Wkf | Wv ----------------
__global__ __launch_bounds__(256) void build_wcat(
    const float* __restrict__ Wq, const float* __restrict__ Wk,
    const float* __restrict__ Wv, const float* __restrict__ Wf,
    float* __restrict__ wcat)
{
    __shared__ float wf_s[64][65];
    __shared__ float wq_s[1024];
    __shared__ float wk_s[1024];
    int k = blockIdx.x;
    int t = threadIdx.x;
    for (int i = t; i < 64 * 64; i += 256) wf_s[i >> 6][i & 63] = Wf[i];
    for (int i = t; i < 1024; i += 256) {
        wq_s[i] = Wq[k * 1024 + i];
        wk_s[i] = Wk[k * 1024 + i];
    }
    __syncthreads();
    for (int n = t; n < 1024; n += 256) {
        int h = n >> 6, f = n & 63;
        const float* wqh = &wq_s[h * 64];
        const float* wkh = &wk_s[h * 64];
        float aq = 0.f, ak = 0.f;
#pragma unroll 16
        for (int e = 0; e < 64; ++e) {
            aq = fmaf(wqh[e], wf_s[e][f], aq);
            ak = fmaf(wkh[e], wf_s[e][f], ak);
        }
        wcat[(size_t)k * N3 + n] = aq;
        wcat[(size_t)k * N3 + 1024 + n] = ak;
    }
    for (int n = t; n < 1024; n += 256) wcat[(size_t)k * N3 + 2048 + n] = Wv[k * 1024 + n];
}

// ------------- transpose + split: in[K][N] fp32 -> out[N][3K] bf16 [hi|hi|lo] -------------
__global__ __launch_bounds__(256) void tsplit(
    const float* __restrict__ in, short* __restrict__ outT, int K, int N)
{
    __shared__ float tile[32][33];
    const int nt = blockIdx.x, ktile = blockIdx.y;
    const int t = threadIdx.x;
    const int r = t >> 3, c4 = (t & 7) * 4;
    float4 v = *(const float4*)&in[(size_t)(ktile * 32 + r) * N + nt * 32 + c4];
    tile[r][c4 + 0] = v.x; tile[r][c4 + 1] = v.y;
    tile[r][c4 + 2] = v.z; tile[r][c4 + 3] = v.w;
    __syncthreads();
    short4v hi, lo;
#pragma unroll
    for (int j = 0; j < 4; ++j) {
        float val = tile[c4 + j][r];
        unsigned short h = f2bf(val);
        hi[j] = (short)h;
        lo[j] = (short)f2bf(val - bf2f(h));
    }
    size_t base = (size_t)(nt * 32 + r) * (size_t)(3 * K) + ktile * 32 + c4;
    *(short4v*)&outT[base] = hi;
    *(short4v*)&outT[base + K] = hi;
    *(short4v*)&outT[base + 2 * K] = lo;
}

// ------------- split x: [rows][1024] fp32 -> [rows][3072] bf16 [hi|lo|hi] -------------
__global__ __launch_bounds__(256) void split_x(
    const float* __restrict__ x, short* __restrict__ xs)
{
    int g = blockIdx.x * 256 + threadIdx.x;
    int row = g >> 8, c4 = (g & 255) * 4;
    float4 v = *(const float4*)&x[(size_t)row * 1024 + c4];
    short4v hi, lo;
    const float* vp = (const float*)&v;
#pragma unroll
    for (int j = 0; j < 4; ++j) {
        unsigned short h = f2bf(vp[j]);
        hi[j] = (short)h;
        lo[j] = (short)f2bf(vp[j] - bf2f(h));
    }
    size_t base = (size_t)row * 3072 + c4;
    *(short4v*)&xs[base] = hi;
    *(short4v*)&xs[base + 1024] = lo;
    *(short4v*)&xs[base + 2048] = hi;
}

// ---------------- bf16 MFMA GEMM: C[M][Nc] = A[M][Kp] @ BT[Nc][Kp]^T ----------------
// 128x128 tile, BK=32, 256 thr = 4 waves (2x2), 16x16x32 MFMA, 4x4 frags/wave.
// LDS: linear dest for global_load_lds (lane-linear, wave-uniform-base-safe);
// XOR slot swizzle (slot ^= (row>>1)&3) on the GLOBAL source and the ds_read
// address (rule 21) -> 2-way (free) read conflicts.
// EPI 0: cols<2048 -> relu(v + bias[col&63]); EPI 1: v + bias[col].
template <int EPI>
__global__ __launch_bounds__(256) void gemm_bf16(
    const short* __restrict__ A, const short* __restrict__ BT,
    float* __restrict__ C, const int Kp, const int Nc,
    const float* __restrict__ bias)
{
    __shared__ short As[128 * 32];
    __shared__ short Bs[128 * 32];
    const int t = threadIdx.x;
    const int m0 = blockIdx.y * 128, n0 = blockIdx.x * 128;
    const int lane = t & 63;
    const int w = t >> 6, wr = w >> 1, wc = w & 1;

    const short* gA[2];
    const short* gB[2];
    int ldsOff[2];
#pragma unroll
    for (int i = 0; i < 2; ++i) {
        int off = (i * 256 + t) * 16;        // byte offset in 8KB tile
        int r = off >> 6;                    // row 0..127 (64B rows)
        int sl = (off >> 4) & 3;             // 16B slot in row
        int sg = sl ^ ((r >> 1) & 3);        // inverse-swizzled source slot
        ldsOff[i] = off >> 1;                // short index
        gA[i] = A + (size_t)(m0 + r) * Kp + sg * 8;
        gB[i] = BT + (size_t)(n0 + r) * Kp + sg * 8;
    }
    int aOff[4], bOff[4];
    const int lr = lane & 15, kl = lane >> 4;
#pragma unroll
    for (int i = 0; i < 4; ++i) {
        int ra = wr * 64 + i * 16 + lr;
        aOff[i] = ra * 32 + (kl ^ ((ra >> 1) & 3)) * 8;
        int rb = wc * 64 + i * 16 + lr;
        bOff[i] = rb * 32 + (kl ^ ((rb >> 1) & 3)) * 8;
    }

    f32x4 acc[4][4];
    const f32x4 zz = {0.f, 0.f, 0.f, 0.f};
#pragma unroll
    for (int i = 0; i < 4; ++i)
#pragma unroll
        for (int j = 0; j < 4; ++j) acc[i][j] = zz;

    for (int kt = 0; kt < Kp; kt += 32) {
        GLOAD16(gA[0] + kt, As + ldsOff[0]);
        GLOAD16(gA[1] + kt, As + ldsOff[1]);
        GLOAD16(gB[0] + kt, Bs + ldsOff[0]);
        GLOAD16(gB[1] + kt, Bs + ldsOff[1]);
        __syncthreads();
        bf16x8 af[4], bfr[4];
#pragma unroll
        for (int i = 0; i < 4; ++i) af[i] = *(const bf16x8*)(As + aOff[i]);
#pragma unroll
        for (int j = 0; j < 4; ++j) bfr[j] = *(const bf16x8*)(Bs + bOff[j]);
#pragma unroll
        for (int i = 0; i < 4; ++i)
#pragma unroll
            for (int j = 0; j < 4; ++j)
                acc[i][j] = __builtin_amdgcn_mfma_f32_16x16x32_bf16(
                    af[i], bfr[j], acc[i][j], 0, 0, 0);
        __syncthreads();
    }

    // epilogue: C/D layout col=lane&15, row=(lane>>4)*4+reg  [m89-verified]
    const int cr = lane >> 4, cc = lane & 15;
#pragma unroll
    for (int i = 0; i < 4; ++i) {
        int mrow0 = m0 + wr * 64 + i * 16 + cr * 4;
#pragma unroll
        for (int j = 0; j < 4; ++j) {
            int col = n0 + wc * 64 + j * 16 + cc;
            float bval = (EPI == 1) ? bias[col] : bias[col & 63];
#pragma unroll
            for (int rg = 0; rg < 4; ++rg) {
                float v = acc[i][j][rg];
                if (EPI == 0) {
                    if (col < 2048) {
                        v += bval;
                        v = v > 0.f ? v : 0.f;
                    }
                } else {
                    v += bval;
                }
                C[(size_t)(mrow0 + rg) * Nc + col] = v;
            }
        }
    }
}

// ---------------- kv partial reduction over L chunks ----------------
// grid (c=16, h=16, b=pair of 2); reduces 256 rows -> kvp[bh][c][64][64], ksp[bh][c][64]
__global__ __launch_bounds__(256) void kv_partial(
    const float* __restrict__ proj, float* __restrict__ kvp, float* __restrict__ ksp)
{
    __shared__ float kf_s[32][64];
    __shared__ float v_s[32][64];
    const int t = threadIdx.x;
    const int c = blockIdx.x, h = blockIdx.y, b = blockIdx.z;
    const int l0 = c * 256;
    const int fq = t >> 4;
    const int dq = t & 15;
    float acc[4][4] = {};
    float ks[4] = {0.f, 0.f, 0.f, 0.f};
    const size_t rowbase = (size_t)b * SEQ * N3;

    for (int lb = 0; lb < 256; lb += 32) {
        __syncthreads();
        for (int i = t; i < 512; i += 256) {
            int r = i >> 4;
            int c4 = (i & 15) * 4;
            const float* rowp = proj + rowbase + (size_t)(l0 + lb + r) * N3 + h * 64;
            *(float4*)&kf_s[r][c4] = *(const float4*)(rowp + 1024 + c4);
            *(float4*)&v_s[r][c4]  = *(const float4*)(rowp + 2048 + c4);
        }
        __syncthreads();
#pragma unroll 8
        for (int l = 0; l < 32; ++l) {
            float4 kf4 = *(const float4*)&kf_s[l][fq * 4];
            float4 v4  = *(const float4*)&v_s[l][dq * 4];
            const float* kfp = (const float*)&kf4;
            const float* vp  = (const float*)&v4;
#pragma unroll
            for (int i = 0; i < 4; ++i) {
#pragma unroll
                for (int j = 0; j < 4; ++j)
                    acc[i][j] = fmaf(kfp[i], vp[j], acc[i][j]);
                if (dq == 0) ks[i] += kfp[i];
            }
        }
    }
    const size_t base = ((size_t)(b * 16 + h) * 16 + c) * 4096;
#pragma unroll
    for (int i = 0; i < 4; ++i)
        *(float4*)&kvp[base + (size_t)(fq * 4 + i) * 64 + dq * 4] = *(float4*)&acc[i][0];
    if (dq == 0) {
        const size_t kb = ((size_t)(b * 16 + h) * 16 + c) * 64;
#pragma unroll
        for (int i = 0; i < 4; ++i) ksp[kb + fq * 4 + i] = ks[i];
    }
}

// nbh = number of (b,h) pairs in this launch (pair of 2 batches -> 32)
__global__ __launch_bounds__(256) void kv_reduce(
    const float* __restrict__ kvp, const float* __restrict__ ksp,
    float* __restrict__ kv, float* __restrict__ ksum, int nbh)
{
    int gid = blockIdx.x * 256 + threadIdx.x;
    if (gid < nbh * 4096) {
        int bh = gid >> 12;
        int fd = gid & 4095;
        float s = 0.f;
#pragma unroll
        for (int c = 0; c < 16; ++c) s += kvp[((size_t)bh * 16 + c) * 4096 + fd];
        kv[gid] = s;
    } else {
        int g = gid - nbh * 4096;
        if (g < nbh * 64) {
            int bh = g >> 6;
            int f = g & 63;
            float s = 0.f;
#pragma unroll
            for (int c = 0; c < 16; ++c) s += ksp[((size_t)bh * 16 + c) * 64 + f];
            ksum[g] = s;
        }
    }
}

// ---- attn apply: (qf.kv)/max(qf.ksum,1e-6) -> asplit [rows][3072] bf16 [hi|lo|hi] ----
__global__ __launch_bounds__(256) void attn_apply(
    const float* __restrict__ proj, const float* __restrict__ kv,
    const float* __restrict__ ksum, short* __restrict__ asplit)
{
    __shared__ float kv_s[64][68];
    __shared__ float qf_s[64][68];
    __shared__ float ks_s[64];
    const int t = threadIdx.x;
    const int b = blockIdx.z, h = blockIdx.y;
    const int l0 = blockIdx.x * 128;
    for (int i = t; i < 4096; i += 256)
        kv_s[i >> 6][i & 63] = kv[(size_t)(b * 16 + h) * 4096 + i];
    if (t < 64) ks_s[t] = ksum[(b * 16 + h) * 64 + t];
    const int rq = t >> 4;
    const int dq = t & 15;

    for (int rb = 0; rb < 128; rb += 64) {
        __syncthreads();
        for (int i = t; i < 1024; i += 256) {
            int r = i >> 4, c4 = (i & 15) * 4;
            *(float4*)&qf_s[r][c4] =
                *(const float4*)(proj + (size_t)(b * SEQ + l0 + rb + r) * N3 + h * 64 + c4);
        }
        __syncthreads();
        float acc[4][4] = {};
        float nrm[4] = {};
        for (int f = 0; f < 64; f += 4) {
            float4 q4[4];
#pragma unroll
            for (int r = 0; r < 4; ++r) q4[r] = *(const float4*)&qf_s[rq * 4 + r][f];
            float4 kvf[4];
#pragma unroll
            for (int j = 0; j < 4; ++j) kvf[j] = *(const float4*)&kv_s[f + j][dq * 4];
#pragma unroll
            for (int r = 0; r < 4; ++r) {
                const float* qp = (const float*)&q4[r];
#pragma unroll
                for (int j = 0; j < 4; ++j) {
                    const float* kp = (const float*)&kvf[j];
#pragma unroll
                    for (int d = 0; d < 4; ++d)
                        acc[r][d] = fmaf(qp[j], kp[d], acc[r][d]);
                    nrm[r] = fmaf(qp[j], ks_s[f + j], nrm[r]);
                }
            }
        }
#pragma unroll
        for (int r = 0; r < 4; ++r) {
            float n = nrm[r] > 1e-6f ? nrm[r] : 1e-6f;
            float inv = 1.f / n;
            short4v hi, lo;
#pragma unroll
            for (int d = 0; d < 4; ++d) {
                float o = acc[r][d] * inv;
                unsigned short hb = f2bf(o);
                hi[d] = (short)hb;
                lo[d] = (short)f2bf(o - bf2f(hb));
            }
            size_t rowo = (size_t)(b * SEQ + l0 + rb + rq * 4 + r) * 3072 + h * 64 + dq * 4;
            *(short4v*)&asplit[rowo] = hi;
            *(short4v*)&asplit[rowo + 1024] = lo;
            *(short4v*)&asplit[rowo + 2048] = hi;
        }
    }
}

extern "C" void kernel_launch(void* const* d_in, const int* in_sizes, int n_in,
                              void* d_out, int out_size, void* d_ws, size_t ws_size,
                              hipStream_t stream)
{
    const float* x  = (const float*)d_in[0];
    const float* Wq = (const float*)d_in[1];
    const float* Wk = (const float*)d_in[2];
    const float* Wv = (const float*)d_in[3];
    const float* Wo = (const float*)d_in[4];
    const float* bo = (const float*)d_in[5];
    const float* Wf = (const float*)d_in[6];
    const float* bf = (const float*)d_in[7];
    float* out = (float*)d_out;
    char* w = (char*)d_ws;

    // workspace layout (bytes), peak ~198 MB (< round-1's proven 232 MB)
    float* wcat = (float*)(w);                  // 1024*3072*4   = 12,582,912
    short* wcsT = (short*)(w + 12582912);       // 3072*3072*2   = 18,874,368
    short* wosT = (short*)(w + 31457280);       // 1024*3072*2   =  6,291,456
    short* xs   = (short*)(w + 37748736);       // 8192*3072*2   =  50,331,648 (reused as asplit)
    float* proj = (float*)(w + 88080384);       // 8192*3072*4   = 100,663,296
    float* kvp  = (float*)(w + 188743680);      // 32*16*4096*4  =   8,388,608
    float* ksp  = (float*)(w + 197132288);      // 32*16*64*4    =     131,072
    float* kv   = (float*)(w + 197263360);      // 32*4096*4     =     524,288
    float* ksum = (float*)(w + 197787648);      // 32*64*4       =       8,192

    build_wcat<<<dim3(1024), 256, 0, stream>>>(Wq, Wk, Wv, Wf, wcat);
    tsplit<<<dim3(96, 32), 256, 0, stream>>>(wcat, wcsT, 1024, 3072);
    tsplit<<<dim3(32, 32), 256, 0, stream>>>(Wo, wosT, 1024, 1024);

    for (int p = 0; p < 2; ++p) {               // 2 batches per pass
        const float* xp = x + (size_t)p * 8192 * 1024;
        float* outp = out + (size_t)p * 8192 * 1024;
        split_x<<<dim3(8192), 256, 0, stream>>>(xp, xs);
        gemm_bf16<0><<<dim3(24, 64), 256, 0, stream>>>(xs, wcsT, proj, 3072, 3072, bf);
        kv_partial<<<dim3(16, 16, 2), 256, 0, stream>>>(proj, kvp, ksp);
        kv_reduce<<<dim3(520), 256, 0, stream>>>(kvp, ksp, kv, ksum, 32);
        attn_apply<<<dim3(32, 16, 2), 256, 0, stream>>>(proj, kv, ksum, xs);
        gemm_bf16<1><<<dim3(8, 64), 256, 0, stream>>>(xs, wosT, outp, 3072, 1024, bo);
    }
}

// Round 9
// 755.917 us; speedup vs baseline: 2.3691x; 1.1068x over previous
//
#include <hip/hip_runtime.h>

// LinearAttentionLayer on MI355X — round 9 (= round 5-8 resubmit; none ran:
// GPU acquisition timeouts x4). BK=64 (halve barrier drains) + XCD-aware block
// swizzle on both MFMA GEMMs. Numerics identical to round 4 (3-term
// split-bf16, absmax 9.77e-4 proven at 836 µs).
//
// Pipeline (weights once, then per batch-pair p in {0,1}, 8192 rows each):
//   build_wcat : wcat[1024][3072] fp32 = [Wq@Wf | Wk@Wf | Wv]
//   tsplit     : wcat -> wcsT[3072][3072] bf16 (transposed, [hi|hi|lo] along k')
//                Wo   -> wosT[1024][3072] bf16
//   split_x    : x_p -> xs[8192][3072] bf16 ([hi|lo|hi] along k')
//   gemm_bf16<0>: proj[8192][3072] fp32 = relu/bias epi( xs @ wcsT^T )   (qf|kf|v)
//   kv_partial/kv_reduce : kv[2,16,64,64], ksum[2,16,64]
//   attn_apply : attn = (qf.kv)/max(qf.ksum,1e-6) -> bf16 split into xs region
//   gemm_bf16<1>: out_p = attn @ Wo + bo
// Split-bf16 GEMM: A'=[hi|lo|hi], B'=[hi|hi|lo] => hi*hi + lo*hi + hi*lo (err ~1e-5).

#define D_MODEL 1024
#define N_HEADS 16
#define BATCH 4
#define SEQ 4096
#define N3 3072

typedef short bf16x8 __attribute__((ext_vector_type(8)));
typedef float f32x4 __attribute__((ext_vector_type(4)));
typedef short short4v __attribute__((ext_vector_type(4)));

__device__ __forceinline__ unsigned short f2bf(float v) {
    unsigned u = __float_as_uint(v);
    unsigned r = (u + 0x7FFF + ((u >> 16) & 1)) >> 16;
    return (unsigned short)r;
}
__device__ __forceinline__ float bf2f(unsigned short b) {
    return __uint_as_float((unsigned)b << 16);
}

#define GLOAD16(gp, lp) __builtin_amdgcn_global_load_lds( \
    (const __attribute__((address_space(1))) void*)(gp),  \
    (__attribute__((address_space(3))) void*)(lp), 16, 0, 0)

// ---------------- Wcat build (fp32): Wqf | Wkf | Wv ----------------
__global__ __launch_bounds__(256) void build_wcat(
    const float* __restrict__ Wq, const float* __restrict__ Wk,
    const float* __restrict__ Wv, const float* __restrict__ Wf,
    float* __restrict__ wcat)
{
    __shared__ float wf_s[64][65];
    __shared__ float wq_s[1024];
    __shared__ float wk_s[1024];
    int k = blockIdx.x;
    int t = threadIdx.x;
    for (int i = t; i < 64 * 64; i += 256) wf_s[i >> 6][i & 63] = Wf[i];
    for (int i = t; i < 1024; i += 256) {
        wq_s[i] = Wq[k * 1024 + i];
        wk_s[i] = Wk[k * 1024 + i];
    }
    __syncthreads();
    for (int n = t; n < 1024; n += 256) {
        int h = n >> 6, f = n & 63;
        const float* wqh = &wq_s[h * 64];
        const float* wkh = &wk_s[h * 64];
        float aq = 0.f, ak = 0.f;
#pragma unroll 16
        for (int e = 0; e < 64; ++e) {
            aq = fmaf(wqh[e], wf_s[e][f], aq);
            ak = fmaf(wkh[e], wf_s[e][f], ak);
        }
        wcat[(size_t)k * N3 + n] = aq;
        wcat[(size_t)k * N3 + 1024 + n] = ak;
    }
    for (int n = t; n < 1024; n += 256) wcat[(size_t)k * N3 + 2048 + n] = Wv[k * 1024 + n];
}

// ------------- transpose + split: in[K][N] fp32 -> out[N][3K] bf16 [hi|hi|lo] -------------
__global__ __launch_bounds__(256) void tsplit(
    const float* __restrict__ in, short* __restrict__ outT, int K, int N)
{
    __shared__ float tile[32][33];
    const int nt = blockIdx.x, ktile = blockIdx.y;
    const int t = threadIdx.x;
    const int r = t >> 3, c4 = (t & 7) * 4;
    float4 v = *(const float4*)&in[(size_t)(ktile * 32 + r) * N + nt * 32 + c4];
    tile[r][c4 + 0] = v.x; tile[r][c4 + 1] = v.y;
    tile[r][c4 + 2] = v.z; tile[r][c4 + 3] = v.w;
    __syncthreads();
    short4v hi, lo;
#pragma unroll
    for (int j = 0; j < 4; ++j) {
        float val = tile[c4 + j][r];
        unsigned short h = f2bf(val);
        hi[j] = (short)h;
        lo[j] = (short)f2bf(val - bf2f(h));
    }
    size_t base = (size_t)(nt * 32 + r) * (size_t)(3 * K) + ktile * 32 + c4;
    *(short4v*)&outT[base] = hi;
    *(short4v*)&outT[base + K] = hi;
    *(short4v*)&outT[base + 2 * K] = lo;
}

// ------------- split x: [rows][1024] fp32 -> [rows][3072] bf16 [hi|lo|hi] -------------
__global__ __launch_bounds__(256) void split_x(
    const float* __restrict__ x, short* __restrict__ xs)
{
    int g = blockIdx.x * 256 + threadIdx.x;
    int row = g >> 8, c4 = (g & 255) * 4;
    float4 v = *(const float4*)&x[(size_t)row * 1024 + c4];
    short4v hi, lo;
    const float* vp = (const float*)&v;
#pragma unroll
    for (int j = 0; j < 4; ++j) {
        unsigned short h = f2bf(vp[j]);
        hi[j] = (short)h;
        lo[j] = (short)f2bf(vp[j] - bf2f(h));
    }
    size_t base = (size_t)row * 3072 + c4;
    *(short4v*)&xs[base] = hi;
    *(short4v*)&xs[base + 1024] = lo;
    *(short4v*)&xs[base + 2048] = hi;
}

// ---------------- bf16 MFMA GEMM: C[M][Nc] = A[M][Kp] @ BT[Nc][Kp]^T ----------------
// 128x128 tile, BK=64, 256 thr = 4 waves (2x2), 16x16x32 MFMA, 4x4 frags/wave,
// 2 k-subtiles per barrier pair (32 MFMA / barrier).
// LDS rows are 128 B (8 x 16 B slots); involution swizzle slot ^= (row&7) applied
// to the GLOBAL source and the ds_read address (linear LDS dest for
// global_load_lds, rule 21). 16B-group of a frag read = slot -> any 8
// consecutive lanes cover all 8 groups -> conflict-free ds_read_b128.
// XCD swizzle: flattened grid, contiguous chunk per XCD (grids are %8==0).
// EPI 0: cols<2048 -> relu(v + bias[col&63]); EPI 1: v + bias[col].
template <int EPI>
__global__ __launch_bounds__(256) void gemm_bf16(
    const short* __restrict__ A, const short* __restrict__ BT,
    float* __restrict__ C, const int Kp, const int Nc,
    const float* __restrict__ bias)
{
    __shared__ short As[128 * 64];
    __shared__ short Bs[128 * 64];
    const int t = threadIdx.x;

    // XCD-aware bijective block swizzle (requires nwg % 8 == 0)
    const int nbx = gridDim.x;
    const int nwg = nbx * gridDim.y;
    const int orig = blockIdx.y * nbx + blockIdx.x;
    const int swz = (orig & 7) * (nwg >> 3) + (orig >> 3);
    const int m0 = (swz / nbx) * 128, n0 = (swz % nbx) * 128;

    const int lane = t & 63;
    const int w = t >> 6, wr = w >> 1, wc = w & 1;

    // staging: 4 chunks of 16B per matrix per thread; linear LDS, swizzled global slot
    const short* gA[4];
    const short* gB[4];
    int ldsOff[4];
#pragma unroll
    for (int i = 0; i < 4; ++i) {
        int off = (i * 256 + t) * 16;        // byte offset in 16KB tile
        int r = off >> 7;                    // row 0..127 (128B rows)
        int sl = (off >> 4) & 7;             // 16B slot in row
        int sg = sl ^ (r & 7);               // inverse-swizzled source slot
        ldsOff[i] = off >> 1;                // short index
        gA[i] = A + (size_t)(m0 + r) * Kp + sg * 8;
        gB[i] = BT + (size_t)(n0 + r) * Kp + sg * 8;
    }
    // fragment ds_read offsets (shorts), k-subtile 0; k-subtile 1 = off ^ 32
    int aOff[4], bOff[4];
    const int lr = lane & 15, kl = lane >> 4;
#pragma unroll
    for (int i = 0; i < 4; ++i) {
        int ra = wr * 64 + i * 16 + lr;
        aOff[i] = ra * 64 + (kl ^ (ra & 7)) * 8;
        int rb = wc * 64 + i * 16 + lr;
        bOff[i] = rb * 64 + (kl ^ (rb & 7)) * 8;
    }

    f32x4 acc[4][4];
    const f32x4 zz = {0.f, 0.f, 0.f, 0.f};
#pragma unroll
    for (int i = 0; i < 4; ++i)
#pragma unroll
        for (int j = 0; j < 4; ++j) acc[i][j] = zz;

    for (int kt = 0; kt < Kp; kt += 64) {
#pragma unroll
        for (int i = 0; i < 4; ++i) GLOAD16(gA[i] + kt, As + ldsOff[i]);
#pragma unroll
        for (int i = 0; i < 4; ++i) GLOAD16(gB[i] + kt, Bs + ldsOff[i]);
        __syncthreads();   // compiler drains vmcnt before s_barrier
#pragma unroll
        for (int ks = 0; ks < 2; ++ks) {
            const int kx = ks * 32;          // short-offset XOR for k-subtile
            bf16x8 af[4], bfr[4];
#pragma unroll
            for (int i = 0; i < 4; ++i) af[i] = *(const bf16x8*)(As + (aOff[i] ^ kx));
#pragma unroll
            for (int j = 0; j < 4; ++j) bfr[j] = *(const bf16x8*)(Bs + (bOff[j] ^ kx));
#pragma unroll
            for (int i = 0; i < 4; ++i)
#pragma unroll
                for (int j = 0; j < 4; ++j)
                    acc[i][j] = __builtin_amdgcn_mfma_f32_16x16x32_bf16(
                        af[i], bfr[j], acc[i][j], 0, 0, 0);
        }
        __syncthreads();
    }

    // epilogue: C/D layout col=lane&15, row=(lane>>4)*4+reg  [m89-verified]
    const int cr = lane >> 4, cc = lane & 15;
#pragma unroll
    for (int i = 0; i < 4; ++i) {
        int mrow0 = m0 + wr * 64 + i * 16 + cr * 4;
#pragma unroll
        for (int j = 0; j < 4; ++j) {
            int col = n0 + wc * 64 + j * 16 + cc;
            float bval = (EPI == 1) ? bias[col] : bias[col & 63];
#pragma unroll
            for (int rg = 0; rg < 4; ++rg) {
                float v = acc[i][j][rg];
                if (EPI == 0) {
                    if (col < 2048) {
                        v += bval;
                        v = v > 0.f ? v : 0.f;
                    }
                } else {
                    v += bval;
                }
                C[(size_t)(mrow0 + rg) * Nc + col] = v;
            }
        }
    }
}

// ---------------- kv partial reduction over L chunks ----------------
// grid (c=16, h=16, b=pair of 2); reduces 256 rows -> kvp[bh][c][64][64], ksp[bh][c][64]
__global__ __launch_bounds__(256) void kv_partial(
    const float* __restrict__ proj, float* __restrict__ kvp, float* __restrict__ ksp)
{
    __shared__ float kf_s[32][64];
    __shared__ float v_s[32][64];
    const int t = threadIdx.x;
    const int c = blockIdx.x, h = blockIdx.y, b = blockIdx.z;
    const int l0 = c * 256;
    const int fq = t >> 4;
    const int dq = t & 15;
    float acc[4][4] = {};
    float ks[4] = {0.f, 0.f, 0.f, 0.f};
    const size_t rowbase = (size_t)b * SEQ * N3;

    for (int lb = 0; lb < 256; lb += 32) {
        __syncthreads();
        for (int i = t; i < 512; i += 256) {
            int r = i >> 4;
            int c4 = (i & 15) * 4;
            const float* rowp = proj + rowbase + (size_t)(l0 + lb + r) * N3 + h * 64;
            *(float4*)&kf_s[r][c4] = *(const float4*)(rowp + 1024 + c4);
            *(float4*)&v_s[r][c4]  = *(const float4*)(rowp + 2048 + c4);
        }
        __syncthreads();
#pragma unroll 8
        for (int l = 0; l < 32; ++l) {
            float4 kf4 = *(const float4*)&kf_s[l][fq * 4];
            float4 v4  = *(const float4*)&v_s[l][dq * 4];
            const float* kfp = (const float*)&kf4;
            const float* vp  = (const float*)&v4;
#pragma unroll
            for (int i = 0; i < 4; ++i) {
#pragma unroll
                for (int j = 0; j < 4; ++j)
                    acc[i][j] = fmaf(kfp[i], vp[j], acc[i][j]);
                if (dq == 0) ks[i] += kfp[i];
            }
        }
    }
    const size_t base = ((size_t)(b * 16 + h) * 16 + c) * 4096;
#pragma unroll
    for (int i = 0; i < 4; ++i)
        *(float4*)&kvp[base + (size_t)(fq * 4 + i) * 64 + dq * 4] = *(float4*)&acc[i][0];
    if (dq == 0) {
        const size_t kb = ((size_t)(b * 16 + h) * 16 + c) * 64;
#pragma unroll
        for (int i = 0; i < 4; ++i) ksp[kb + fq * 4 + i] = ks[i];
    }
}

// nbh = number of (b,h) pairs in this launch (pair of 2 batches -> 32)
__global__ __launch_bounds__(256) void kv_reduce(
    const float* __restrict__ kvp, const float* __restrict__ ksp,
    float* __restrict__ kv, float* __restrict__ ksum, int nbh)
{
    int gid = blockIdx.x * 256 + threadIdx.x;
    if (gid < nbh * 4096) {
        int bh = gid >> 12;
        int fd = gid & 4095;
        float s = 0.f;
#pragma unroll
        for (int c = 0; c < 16; ++c) s += kvp[((size_t)bh * 16 + c) * 4096 + fd];
        kv[gid] = s;
    } else {
        int g = gid - nbh * 4096;
        if (g < nbh * 64) {
            int bh = g >> 6;
            int f = g & 63;
            float s = 0.f;
#pragma unroll
            for (int c = 0; c < 16; ++c) s += ksp[((size_t)bh * 16 + c) * 64 + f];
            ksum[g] = s;
        }
    }
}

// ---- attn apply: (qf.kv)/max(qf.ksum,1e-6) -> asplit [rows][3072] bf16 [hi|lo|hi] ----
__global__ __launch_bounds__(256) void attn_apply(
    const float* __restrict__ proj, const float* __restrict__ kv,
    const float* __restrict__ ksum, short* __restrict__ asplit)
{
    __shared__ float kv_s[64][68];
    __shared__ float qf_s[64][68];
    __shared__ float ks_s[64];
    const int t = threadIdx.x;
    const int b = blockIdx.z, h = blockIdx.y;
    const int l0 = blockIdx.x * 128;
    for (int i = t; i < 4096; i += 256)
        kv_s[i >> 6][i & 63] = kv[(size_t)(b * 16 + h) * 4096 + i];
    if (t < 64) ks_s[t] = ksum[(b * 16 + h) * 64 + t];
    const int rq = t >> 4;
    const int dq = t & 15;

    for (int rb = 0; rb < 128; rb += 64) {
        __syncthreads();
        for (int i = t; i < 1024; i += 256) {
            int r = i >> 4, c4 = (i & 15) * 4;
            *(float4*)&qf_s[r][c4] =
                *(const float4*)(proj + (size_t)(b * SEQ + l0 + rb + r) * N3 + h * 64 + c4);
        }
        __syncthreads();
        float acc[4][4] = {};
        float nrm[4] = {};
        for (int f = 0; f < 64; f += 4) {
            float4 q4[4];
#pragma unroll
            for (int r = 0; r < 4; ++r) q4[r] = *(const float4*)&qf_s[rq * 4 + r][f];
            float4 kvf[4];
#pragma unroll
            for (int j = 0; j < 4; ++j) kvf[j] = *(const float4*)&kv_s[f + j][dq * 4];
#pragma unroll
            for (int r = 0; r < 4; ++r) {
                const float* qp = (const float*)&q4[r];
#pragma unroll
                for (int j = 0; j < 4; ++j) {
                    const float* kp = (const float*)&kvf[j];
#pragma unroll
                    for (int d = 0; d < 4; ++d)
                        acc[r][d] = fmaf(qp[j], kp[d], acc[r][d]);
                    nrm[r] = fmaf(qp[j], ks_s[f + j], nrm[r]);
                }
            }
        }
#pragma unroll
        for (int r = 0; r < 4; ++r) {
            float n = nrm[r] > 1e-6f ? nrm[r] : 1e-6f;
            float inv = 1.f / n;
            short4v hi, lo;
#pragma unroll
            for (int d = 0; d < 4; ++d) {
                float o = acc[r][d] * inv;
                unsigned short hb = f2bf(o);
                hi[d] = (short)hb;
                lo[d] = (short)f2bf(o - bf2f(hb));
            }
            size_t rowo = (size_t)(b * SEQ + l0 + rb + rq * 4 + r) * 3072 + h * 64 + dq * 4;
            *(short4v*)&asplit[rowo] = hi;
            *(short4v*)&asplit[rowo + 1024] = lo;
            *(short4v*)&asplit[rowo + 2048] = hi;
        }
    }
}

extern "C" void kernel_launch(void* const* d_in, const int* in_sizes, int n_in,
                              void* d_out, int out_size, void* d_ws, size_t ws_size,
                              hipStream_t stream)
{
    const float* x  = (const float*)d_in[0];
    const float* Wq = (const float*)d_in[1];
    const float* Wk = (const float*)d_in[2];
    const float* Wv = (const float*)d_in[3];
    const float* Wo = (const float*)d_in[4];
    const float* bo = (const float*)d_in[5];
    const float* Wf = (const float*)d_in[6];
    const float* bf = (const float*)d_in[7];
    float* out = (float*)d_out;
    char* w = (char*)d_ws;

    // workspace layout (bytes), peak ~198 MB (< round-1's proven 232 MB)
    float* wcat = (float*)(w);                  // 1024*3072*4   = 12,582,912
    short* wcsT = (short*)(w + 12582912);       // 3072*3072*2   = 18,874,368
    short* wosT = (short*)(w + 31457280);       // 1024*3072*2   =  6,291,456
    short* xs   = (short*)(w + 37748736);       // 8192*3072*2   =  50,331,648 (reused as asplit)
    float* proj = (float*)(w + 88080384);       // 8192*3072*4   = 100,663,296
    float* kvp  = (float*)(w + 188743680);      // 32*16*4096*4  =   8,388,608
    float* ksp  = (float*)(w + 197132288);      // 32*16*64*4    =     131,072
    float* kv   = (float*)(w + 197263360);      // 32*4096*4     =     524,288
    float* ksum = (float*)(w + 197787648);      // 32*64*4       =       8,192

    build_wcat<<<dim3(1024), 256, 0, stream>>>(Wq, Wk, Wv, Wf, wcat);
    tsplit<<<dim3(96, 32), 256, 0, stream>>>(wcat, wcsT, 1024, 3072);
    tsplit<<<dim3(32, 32), 256, 0, stream>>>(Wo, wosT, 1024, 1024);

    for (int p = 0; p < 2; ++p) {               // 2 batches per pass
        const float* xp = x + (size_t)p * 8192 * 1024;
        float* outp = out + (size_t)p * 8192 * 1024;
        split_x<<<dim3(8192), 256, 0, stream>>>(xp, xs);
        gemm_bf16<0><<<dim3(24, 64), 256, 0, stream>>>(xs, wcsT, proj, 3072, 3072, bf);
        kv_partial<<<dim3(16, 16, 2), 256, 0, stream>>>(proj, kvp, ksp);
        kv_reduce<<<dim3(520), 256, 0, stream>>>(kvp, ksp, kv, ksum, 32);
        attn_apply<<<dim3(32, 16, 2), 256, 0, stream>>>(proj, kv, ksum, xs);
        gemm_bf16<1><<<dim3(8, 64), 256, 0, stream>>>(xs, wosT, outp, 3072, 1024, bo);
    }
}